// Round 8
// baseline (148.869 us; speedup 1.0000x reference)
//
#include <hip/hip_runtime.h>
#include <hip/hip_bf16.h>
#include <hip/hip_fp16.h>
#include <math.h>

#define BATCH 64
#define LAT   256
#define DVOX  64
#define VOX   (DVOX*DVOX*DVOX)   // 262144

typedef __attribute__((ext_vector_type(8))) short short8;
typedef __attribute__((ext_vector_type(4))) float f32x4;

// ---------------- kernel 0: enc -> bf16, build rotation matrices -----------
__global__ void prep_kernel(const float* __restrict__ enc,      // [64,256]
                            const float* __restrict__ angles,   // [64,3]
                            unsigned short* __restrict__ encB,  // [64,256] bf16 bits
                            float* __restrict__ Rmat) {         // [64,9]
    int tid = threadIdx.x;
    for (int idx = tid; idx < BATCH * LAT; idx += blockDim.x) {
        __hip_bfloat16 h = __float2bfloat16(enc[idx]);
        encB[idx] = *reinterpret_cast<unsigned short*>(&h);
    }
    if (tid < BATCH) {
        float ax = angles[tid*3+0], ay = angles[tid*3+1], az = angles[tid*3+2];
        float cx = cosf(ax), sx = sinf(ax);
        float cy = cosf(ay), sy = sinf(ay);
        float cz = cosf(az), sz = sinf(az);
        float* R = Rmat + tid * 9;
        R[0] = cz*cy;  R[1] = cz*sy*sx - sz*cx;  R[2] = cz*sy*cx + sz*sx;
        R[3] = sz*cy;  R[4] = sz*sy*sx + cz*cx;  R[5] = sz*sy*cx - cz*sx;
        R[6] = -sy;    R[7] = cy*sx;             R[8] = cy*cx;
    }
}

// ---------------- kernel 1: MFMA GEMM + sigmoid^8 -> fp16 voxels -----------
// 64-col span per wave = 4 interleaved 16-col tiles; float4 W loads feed all
// 4 B-frags. Ping-pong W buffers (no register copies). bf16 conversion =
// v_perm_b32 pack of high halves with +0x8000 round-half-up (1 add-pair +
// 1 perm per bf16x2). Epilogue: 4 cols -> one contiguous 8B store.
__global__ __launch_bounds__(256, 2) void gemm_mfma_kernel(
        const unsigned short* __restrict__ encB,  // [64,256] bf16
        const float* __restrict__ W,              // [256, 262144]
        const float* __restrict__ bias,           // [262144]
        __half* __restrict__ vox) {               // [64, 262144] fp16
    int wave = threadIdx.x >> 6;
    int lane = threadIdx.x & 63;
    int l15 = lane & 15, l4 = lane >> 4;
    int n4 = blockIdx.x * 256 + wave * 64 + 4 * l15;  // cols n4..n4+3

    f32x4 acc[4][4];   // [tile][mt]
#pragma unroll
    for (int t = 0; t < 4; ++t)
#pragma unroll
        for (int mt = 0; mt < 4; ++mt) acc[t][mt] = (f32x4){0.f, 0.f, 0.f, 0.f};

    const unsigned short* ap = encB + l15 * LAT + l4 * 8;
    const float* wp = W + (size_t)(l4 * 8) * VOX + n4;

    float4 wA[8], wB[8];
#pragma unroll
    for (int j = 0; j < 8; ++j)
        wA[j] = *(const float4*)(wp + (size_t)j * VOX);

    auto consume = [&](const float4* w, int kb) {
        short8 a[4];
#pragma unroll
        for (int mt = 0; mt < 4; ++mt)
            a[mt] = *(const short8*)(ap + mt * 16 * LAT + kb);
        short8 bf[4];
#pragma unroll
        for (int t = 0; t < 4; ++t) {
            unsigned bw[4];
#pragma unroll
            for (int dw = 0; dw < 4; ++dw) {
                unsigned u0 = __float_as_uint(((const float*)&w[2 * dw])[t])     + 0x8000u;
                unsigned u1 = __float_as_uint(((const float*)&w[2 * dw + 1])[t]) + 0x8000u;
                bw[dw] = __builtin_amdgcn_perm(u1, u0, 0x07060302u);  // hi16(u0)|hi16(u1)<<16
            }
            bf[t] = *reinterpret_cast<short8*>(bw);
        }
#pragma unroll
        for (int t = 0; t < 4; ++t)
#pragma unroll
            for (int mt = 0; mt < 4; ++mt)
                acc[t][mt] = __builtin_amdgcn_mfma_f32_16x16x32_bf16(a[mt], bf[t], acc[t][mt], 0, 0, 0);
    };

#pragma unroll
    for (int kb2 = 0; kb2 < LAT; kb2 += 64) {
        {   // prefetch odd buffer (kb2+32 always < LAT)
            const float* q = wp + (size_t)(kb2 + 32) * VOX;
#pragma unroll
            for (int j = 0; j < 8; ++j) wB[j] = *(const float4*)(q + (size_t)j * VOX);
        }
        consume(wA, kb2);
        if (kb2 + 64 < LAT) {
            const float* q = wp + (size_t)(kb2 + 64) * VOX;
#pragma unroll
            for (int j = 0; j < 8; ++j) wA[j] = *(const float4*)(q + (size_t)j * VOX);
        }
        consume(wB, kb2 + 32);
    }

    float4 bv = *(const float4*)(bias + n4);
#pragma unroll
    for (int mt = 0; mt < 4; ++mt) {
#pragma unroll
        for (int r = 0; r < 4; ++r) {
            int b = mt * 16 + l4 * 4 + r;
            float s[4];
#pragma unroll
            for (int t = 0; t < 4; ++t) {
                float x = acc[t][mt][r] + ((const float*)&bv)[t];
                float v = 1.f / (1.f + __expf(-x));   // sigmoid
                v = v * v; v = v * v; v = v * v;      // ^8
                s[t] = v;
            }
            __half2 h01 = __floats2half2_rn(s[0], s[1]);
            __half2 h23 = __floats2half2_rn(s[2], s[3]);
            uint2 pk;
            pk.x = *reinterpret_cast<unsigned*>(&h01);
            pk.y = *reinterpret_cast<unsigned*>(&h23);
            *reinterpret_cast<uint2*>(vox + (size_t)b * VOX + n4) = pk;
        }
    }
}

// ---------------- kernel 2: 4-wave cooperative LDS-brick resample ----------
// Staging: each brick row's 36B z-window is loaded by a QUAD of lanes
// (dwordx2 each + 1 extra dword for m==3), so every load instr covers 16
// rows x 32B contiguous (dense lines) instead of 64 rows x 4B (TA-serial).
// Pack gets the neighbor dword via __shfl(lane+1) (in-row for m<3; m==3
// holds dword 8 itself). Brick: 16x16x16 z-pair entries, row stride 17.
// Sampling and 4-segment fold as before. Cross-chunk load prefetch.
__device__ __forceinline__ float zlerp(unsigned e, float fz) {
    __half2 h = *reinterpret_cast<__half2*>(&e);
    float2 f = __half22float2(h);
    return f.x + (f.y - f.x) * fz;
}

__global__ __launch_bounds__(256) void render_lds_kernel(
        const __half* __restrict__ vox,   // [64, 262144] fp16
        const float* __restrict__ Rmat,   // [64,9]
        float* __restrict__ out) {        // [64,1,64,64]
    __shared__ unsigned sV[16 * 16 * 17]; // 17408 B brick, row stride 17
    __shared__ float sT[4][64], sE[4][64];

    int bid  = blockIdx.x;
    int b    = bid & 63;                  // bid%8 == b%8 -> XCD affinity
    int tile = bid >> 6;
    int t    = threadIdx.x;
    int lane = t & 63;
    int pix  = t & 63, seg = t >> 6;      // seg == wave id
    int m    = t & 3,  rq  = t >> 2;      // staging quad-lane / row index
    int i0 = (tile >> 3) * 8, j0 = (tile & 7) * 8;
    int i = i0 + (pix >> 3);
    int j = j0 + (pix & 7);

    const float* Rb = Rmat + b * 9;       // uniform -> scalar loads
    float R0 = Rb[0], R1 = Rb[1], R2 = Rb[2];
    float R3 = Rb[3], R4 = Rb[4], R5 = Rb[5];
    float R6 = Rb[6], R7 = Rb[7], R8 = Rb[8];

    const float c = (DVOX - 1) * 0.5f;    // 31.5
    float di = (float)i - c, dj = (float)j - c;
    float xb = fmaf(R0, di, fmaf(R1, dj, c));
    float yb = fmaf(R3, di, fmaf(R4, dj, c));
    float zb = fmaf(R6, di, fmaf(R7, dj, c));

    float dic = (float)i0 + 3.5f - c;     // tile-center offsets (uniform)
    float djc = (float)j0 + 3.5f - c;
    float hwx = 3.5f * (fabsf(R0) + fabsf(R1) + fabsf(R2)) + 1e-3f;
    float hwy = 3.5f * (fabsf(R3) + fabsf(R4) + fabsf(R5)) + 1e-3f;
    float hwz = 3.5f * (fabsf(R6) + fabsf(R7) + fabsf(R8)) + 1e-3f;

    const unsigned short* V = (const unsigned short*)vox + (size_t)b * VOX;

    unsigned D0[4], D1[4], D2[4];         // staged regs for chunk "_n"
    int xlo_n, ylo_n, zlo_n, s_n;

    auto bbox = [&](int ch) {
        float dkc = (float)(ch * 8) + 3.5f - c;
        float xc = fmaf(R0, dic, fmaf(R1, djc, fmaf(R2, dkc, c)));
        float yc = fmaf(R3, dic, fmaf(R4, djc, fmaf(R5, dkc, c)));
        float zc = fmaf(R6, dic, fmaf(R7, djc, fmaf(R8, dkc, c)));
        xlo_n = (int)floorf(xc - hwx);
        ylo_n = (int)floorf(yc - hwy);
        zlo_n = (int)floorf(zc - hwz);
        s_n   = zlo_n & ~1;
    };
    auto issue = [&]() {
#pragma unroll
        for (int p = 0; p < 4; ++p) {
            int r = 64 * p + rq;
            int rx = r >> 4, ry = r & 15;
            int gxc = min(max(xlo_n + rx, 0), DVOX - 1);
            int gyc = min(max(ylo_n + ry, 0), DVOX - 1);
            const unsigned* pp = (const unsigned*)V + ((gxc << 11) + (gyc << 5) + (s_n >> 1));
            uint2 dd = *(const uint2*)(pp + 2 * m);
            D0[p] = dd.x; D1[p] = dd.y;
            if (m == 3) D2[p] = pp[8];
        }
    };

    bbox(7); issue();
    int xlo = xlo_n, ylo = ylo_n, zlo = zlo_n, s = s_n;

    float img = 0.f;                      // live in wave 0 only
#pragma unroll 1
    for (int ch = 7; ch >= 0; --ch) {     // back-to-front chunks of 8 z
        bool zint = (zlo >= 0) && (zlo + 17 <= DVOX);
        int  odd  = zlo & 1;

        // ---- pack 4 quad-rows into the brick ------------------------------
#pragma unroll
        for (int p = 0; p < 4; ++p) {
            int r = 64 * p + rq;
            int rx = r >> 4, ry = r & 15;
            bool rv = ((unsigned)(xlo + rx) < (unsigned)DVOX) &
                      ((unsigned)(ylo + ry) < (unsigned)DVOX);
            unsigned d0 = D0[p], d1 = D1[p];
            unsigned dnb = __shfl(D0[p], (lane + 1) & 63);  // neighbor d0 (m<3)
            unsigned dn = (m == 3) ? D2[p] : dnb;
            if (!zint) {                  // block-uniform branch
                auto mz = [&](int off) {
                    int h0 = s + 2 * off;
                    return (((unsigned)h0 < (unsigned)DVOX) ? 0x0000FFFFu : 0u)
                         | (((unsigned)(h0 + 1) < (unsigned)DVOX) ? 0xFFFF0000u : 0u);
                };
                d0 &= mz(2 * m); d1 &= mz(2 * m + 1); dn &= mz(2 * m + 2);
            }
            unsigned rvm = rv ? 0xFFFFFFFFu : 0u;
            d0 &= rvm; d1 &= rvm; dn &= rvm;

            unsigned A0 = (d0 >> 16) | (d1 << 16);   // v_alignbit
            unsigned A1 = (d1 >> 16) | (dn << 16);

            unsigned* wrow = sV + r * 17 + 4 * m;
            if (odd) { wrow[0] = A0; wrow[1] = d1; wrow[2] = A1; wrow[3] = dn; }
            else     { wrow[0] = d0; wrow[1] = A0; wrow[2] = d1; wrow[3] = A1; }
        }

        // ---- issue NEXT chunk's loads (latency hides under sampling) ------
        if (ch > 0) { bbox(ch - 1); issue(); }
        __syncthreads();                  // brick ready

        // ---- sample this wave's 2-z segment, back-to-front ----------------
        float T = 1.f, E = 0.f;
        int k0 = ch * 8;
#pragma unroll
        for (int q = 1; q >= 0; --q) {    // kk = 2*seg+1, then 2*seg
            int kk = 2 * seg + q;
            float dk = (float)(k0 + kk) - c;
            float x = fmaf(R2, dk, xb);
            float y = fmaf(R5, dk, yb);
            float z = fmaf(R8, dk, zb);

            float xf = floorf(x), yf = floorf(y), zf = floorf(z);
            float fx = x - xf, fy = y - yf, fz = z - zf;
            int xi = (int)xf - xlo;       // [0,14]
            int yi = (int)yf - ylo;
            int zi = (int)zf - zlo;
            const unsigned* e = sV + (xi * 272 + yi * 17 + zi);

            float c00 = zlerp(e[0],   fz);   // (x0,y0)
            float c01 = zlerp(e[17],  fz);   // (x0,y1)
            float c10 = zlerp(e[272], fz);   // (x1,y0)
            float c11 = zlerp(e[289], fz);   // (x1,y1)
            float c0 = c00 + (c01 - c00) * fy;
            float c1 = c10 + (c11 - c10) * fy;
            float a  = c0  + (c1  - c0 ) * fx;

            E = E * (1.f - a) + a;
            T *= (1.f - a);
        }
        sT[seg][pix] = T;
        sE[seg][pix] = E;
        __syncthreads();                  // segments ready; sV reads done

        // ---- wave 0 folds the 4 segments (back seg 3 first) ---------------
        if (seg == 0) {
            float im = img;
#pragma unroll
            for (int ss = 3; ss >= 0; --ss)
                im = fmaf(sT[ss][pix], im, sE[ss][pix]);
            img = im;
        }
        // next chunk's sT/sE writes are ordered after this fold by the
        // post-pack __syncthreads() of the next iteration.

        xlo = xlo_n; ylo = ylo_n; zlo = zlo_n; s = s_n;
    }

    if (seg == 0)
        out[b * (DVOX * DVOX) + i * DVOX + j] = 2.f * img - 1.f;
}

// ---------------------------------------------------------------------------
extern "C" void kernel_launch(void* const* d_in, const int* in_sizes, int n_in,
                              void* d_out, int out_size, void* d_ws, size_t ws_size,
                              hipStream_t stream) {
    const float* enc    = (const float*)d_in[0];
    const float* W      = (const float*)d_in[1];
    const float* bias   = (const float*)d_in[2];
    const float* angles = (const float*)d_in[3];
    float* out = (float*)d_out;

    char* ws = (char*)d_ws;
    unsigned short* encB = (unsigned short*)ws;           // 32 KB
    float* Rmat          = (float*)(ws + 32768);          // 2.3 KB
    __half* vox          = (__half*)(ws + 65536);         // 32 MiB

    prep_kernel<<<1, 256, 0, stream>>>(enc, angles, encB, Rmat);
    gemm_mfma_kernel<<<VOX / 256, 256, 0, stream>>>(encB, W, bias, vox);
    render_lds_kernel<<<BATCH * 64, 256, 0, stream>>>(vox, Rmat, out);
}